// Round 16
// baseline (2725.640 us; speedup 1.0000x reference)
//
#include <hip/hip_runtime.h>
#include <hip/hip_bf16.h>

#define NP   16384
#define KNN  32
#define HDIM 128
#define ODIM 64

typedef __attribute__((ext_vector_type(8))) short bf16x8;
typedef __attribute__((ext_vector_type(4))) float f32x4;

// ---------------- split fp32 -> bf16 (hi, lo) planes ----------------
__global__ __launch_bounds__(256)
void split_kernel(const float* __restrict__ X, unsigned short* __restrict__ hi,
                  unsigned short* __restrict__ lo, int n4) {
    const int i = blockIdx.x * 256 + threadIdx.x;
    if (i >= n4) return;
    const float4 v = reinterpret_cast<const float4*>(X)[i];
    const float vv[4] = {v.x, v.y, v.z, v.w};
    ushort4 h, l;
    unsigned short* hp = &h.x;
    unsigned short* lp = &l.x;
    #pragma unroll
    for (int c = 0; c < 4; ++c) {
        __hip_bfloat16 hb = __float2bfloat16(vv[c]);           // RNE
        const float hf = __bfloat162float(hb);
        __hip_bfloat16 lb = __float2bfloat16(vv[c] - hf);
        hp[c] = *reinterpret_cast<unsigned short*>(&hb);
        lp[c] = *reinterpret_cast<unsigned short*>(&lb);
    }
    reinterpret_cast<ushort4*>(hi)[i] = h;
    reinterpret_cast<ushort4*>(lo)[i] = l;
}

// ---------------- squared norms (fp32, exact as before) ----------------
template<int D>
__global__ __launch_bounds__(256)
void sq_kernel(const float* __restrict__ X, float* __restrict__ sq) {
    const int lane = threadIdx.x & 63;
    const int row  = blockIdx.x * 4 + (threadIdx.x >> 6);
    float s = 0.f;
    #pragma unroll
    for (int d = lane; d < D; d += 64) {
        const float v = X[(size_t)row * D + d];
        s = fmaf(v, v, s);
    }
    #pragma unroll
    for (int off = 32; off; off >>= 1) s += __shfl_down(s, off);
    if (lane == 0) sq[row] = s;
}

// ---------------- top-32 neighbors: MFMA scores + sorted register top-k ----
// score = hi.hi + hi.lo + lo.hi (bf16 split, fp32 accum) - 0.5*sq_j.
// TI=32 rows/block, JC=128 cols/tile, 8 waves; wave w owns cols [16w,16w+16).
// B-fragments loaded DIRECTLY from global into the MFMA per-lane layout
// (col=16w+(lane&15), k=32s+8*(lane>>4)) -- no xj LDS at all (zero cross-wave
// reuse), no staging regs.  LDS = padded score-exchange only (16.5 KB) ->
// occupancy is VGPR-bound (~2 blocks/CU).  Next-tile B loads issue after B1,
// hidden under the scan.  Scores bit-identical to R14/R15.
template<int D>
__global__ __launch_bounds__(512)
void topk_kernel(const unsigned short* __restrict__ Xhi,
                 const unsigned short* __restrict__ Xlo,
                 const float* __restrict__ sq, int* __restrict__ topIdx) {
    constexpr int TI = 32, JC = 128, SS = JC + 1;
    constexpr int NT = NP / JC;
    constexpr int KS = D / 32;          // MFMA k-steps
    __shared__ float scoresR[TI * SS];  // [row][col], stride 129 (conflict-free)

    const int t = threadIdx.x;
    const int lane = t & 63;
    const int waveU = __builtin_amdgcn_readfirstlane(t >> 6);
    const int rowBase = blockIdx.x * TI;
    const int l15 = lane & 15, l4 = lane >> 4;
    const float INF = __builtin_inff();
    const int jcol = 16 * waveU + l15;          // this lane's column (0..127)
    const size_t bOff = (size_t)jcol * D + 8 * l4;   // fragment base within a tile

    // A fragments (32 xi rows), resident in registers for the whole kernel.
    bf16x8 Ahi[2][KS], Alo[2][KS];
    #pragma unroll
    for (int rb = 0; rb < 2; ++rb)
        #pragma unroll
        for (int s = 0; s < KS; ++s) {
            const size_t off = (size_t)(rowBase + 16 * rb + l15) * D + 32 * s + 8 * l4;
            Ahi[rb][s] = *reinterpret_cast<const bf16x8*>(Xhi + off);
            Alo[rb][s] = *reinterpret_cast<const bf16x8*>(Xlo + off);
        }

    float tv[4]; int tidx[4]; float minv[4];
    #pragma unroll
    for (int r = 0; r < 4; ++r) { tv[r] = -INF; tidx[r] = 0x7fffffff; minv[r] = -INF; }

    // prologue: B fragments for tile 0
    bf16x8 Bh[KS], Bl[KS];
    #pragma unroll
    for (int s = 0; s < KS; ++s) {
        Bh[s] = *reinterpret_cast<const bf16x8*>(Xhi + bOff + 32 * s);
        Bl[s] = *reinterpret_cast<const bf16x8*>(Xlo + bOff + 32 * s);
    }

    for (int it = 0; it < NT; ++it) {
        const int jb = it * JC;
        const float sub0 = 0.5f * sq[jb + lane];
        const float sub1 = 0.5f * sq[jb + 64 + lane];

        // MFMA: this wave's 16 cols x 32 rows; 3 independent chains per block
        f32x4 Ca0 = {0,0,0,0}, Cb0 = {0,0,0,0}, Cc0 = {0,0,0,0};
        f32x4 Ca1 = {0,0,0,0}, Cb1 = {0,0,0,0}, Cc1 = {0,0,0,0};
        #pragma unroll
        for (int s = 0; s < KS; ++s) {
            Ca0 = __builtin_amdgcn_mfma_f32_16x16x32_bf16(Ahi[0][s], Bh[s], Ca0, 0, 0, 0);
            Ca1 = __builtin_amdgcn_mfma_f32_16x16x32_bf16(Ahi[1][s], Bh[s], Ca1, 0, 0, 0);
            Cb0 = __builtin_amdgcn_mfma_f32_16x16x32_bf16(Ahi[0][s], Bl[s], Cb0, 0, 0, 0);
            Cb1 = __builtin_amdgcn_mfma_f32_16x16x32_bf16(Ahi[1][s], Bl[s], Cb1, 0, 0, 0);
            Cc0 = __builtin_amdgcn_mfma_f32_16x16x32_bf16(Alo[0][s], Bh[s], Cc0, 0, 0, 0);
            Cc1 = __builtin_amdgcn_mfma_f32_16x16x32_bf16(Alo[1][s], Bh[s], Cc1, 0, 0, 0);
        }
        // scatter C -> scoresR[row][col] (stride 129: rows land on distinct banks)
        #pragma unroll
        for (int r = 0; r < 4; ++r) {
            scoresR[(4 * l4 + r) * SS + jcol]      = (Ca0[r] + Cb0[r]) + Cc0[r];
            scoresR[(16 + 4 * l4 + r) * SS + jcol] = (Ca1[r] + Cb1[r]) + Cc1[r];
        }
        __syncthreads();                 // B1: score writes visible

        // issue next tile's B fragments now; latency hides under the scan
        if (it + 1 < NT) {
            const size_t nb = bOff + (size_t)(jb + JC) * D;
            #pragma unroll
            for (int s = 0; s < KS; ++s) {
                Bh[s] = *reinterpret_cast<const bf16x8*>(Xhi + nb + 32 * s);
                Bl[s] = *reinterpret_cast<const bf16x8*>(Xlo + nb + 32 * s);
            }
        }

        // scan: sorted-insert; wave owns rows [4*waveU, 4*waveU+4)
        #pragma unroll
        for (int h = 0; h < 2; ++h) {
            float sv[4];
            unsigned long long m[4];
            #pragma unroll
            for (int r = 0; r < 4; ++r) {
                sv[r] = scoresR[(waveU * 4 + r) * SS + h * 64 + lane]
                      - (h ? sub1 : sub0);
                m[r] = __ballot(sv[r] > minv[r]);
            }
            while (m[0] | m[1] | m[2] | m[3]) {
                #pragma unroll
                for (int r = 0; r < 4; ++r) {
                    if (m[r]) {
                        const int l = __builtin_ctzll(m[r]);  // ascending j => stable
                        m[r] &= m[r] - 1;
                        const float cv = __shfl(sv[r], l);
                        const int   cj = jb + h * 64 + l;
                        const float upv = __shfl_up(tv[r], 1);   // hoisted off chain
                        const int   upi = __shfl_up(tidx[r], 1);
                        const bool ge = (lane < KNN) && (tv[r] >= cv);
                        const int p = __popcll(__ballot(ge));    // ==32 -> no-op
                        if (lane == p)                   { tv[r] = cv;  tidx[r] = cj; }
                        else if (lane > p && lane < KNN) { tv[r] = upv; tidx[r] = upi; }
                    }
                }
            }
        }
        #pragma unroll
        for (int r = 0; r < 4; ++r)
            minv[r] = __shfl(tv[r], KNN - 1);   // exact refresh, once per tile

        __syncthreads();                 // B2: scan reads done before next scatter
    }

    if (lane < KNN) {
        #pragma unroll
        for (int r = 0; r < 4; ++r)
            topIdx[(size_t)(rowBase + waveU * 4 + r) * KNN + lane] = tidx[r];
    }
}

// ---------------- gather + MLP + pool + out (unchanged) ----------------
template<int D, int LAYER>
__global__ __launch_bounds__(512)
void mlp_kernel(const float* __restrict__ X, const int* __restrict__ topIdx,
                const float* __restrict__ W, const float* __restrict__ W2,
                float* __restrict__ out) {
    constexpr int RPB = 2, WPR = 4, KPT = 8;
    constexpr int W2C  = HDIM + D;
    constexpr int SPL2 = 512 / (RPB * ODIM);   // 4
    constexpr int CL   = W2C / SPL2;
    __shared__ float AT[D * HDIM];             // [d][hh]: B^T first, then A^T
    __shared__ float xi[RPB][D];
    __shared__ float part[RPB][WPR][HDIM];

    const int t = threadIdx.x;
    const int lane = t & 63;
    const int waveU = __builtin_amdgcn_readfirstlane(t >> 6);
    const int rowBase = blockIdx.x * RPB;
    const int row = waveU / WPR;
    const int wkb = waveU % WPR;
    const int hh2 = 2 * lane;

    if (t < RPB * D / 4) {
        const int i = t / (D / 4), dg = t % (D / 4);
        const float4 v = *reinterpret_cast<const float4*>(
            X + (size_t)(rowBase + i) * D + 4 * dg);
        xi[i][4 * dg + 0] = v.x; xi[i][4 * dg + 1] = v.y;
        xi[i][4 * dg + 2] = v.z; xi[i][4 * dg + 3] = v.w;
    }
    for (int e = t; e < HDIM * D / 4; e += 512) {
        const int hh = e % HDIM, dg = e / HDIM;
        const float4 v = *reinterpret_cast<const float4*>(
            W + (size_t)hh * (2 * D) + D + 4 * dg);          // B = W[:, D:2D]
        AT[(4 * dg + 0) * HDIM + hh] = v.x; AT[(4 * dg + 1) * HDIM + hh] = v.y;
        AT[(4 * dg + 2) * HDIM + hh] = v.z; AT[(4 * dg + 3) * HDIM + hh] = v.w;
    }
    __syncthreads();

    float hs0 = 0.f, hs1 = 0.f;
    #pragma unroll 8
    for (int d = 0; d < D; ++d) {
        const float a = xi[row][d];
        const float2 b = *reinterpret_cast<const float2*>(&AT[d * HDIM + hh2]);
        hs0 = fmaf(b.x, a, hs0);
        hs1 = fmaf(b.y, a, hs1);
    }
    __syncthreads();

    for (int e = t; e < HDIM * D / 4; e += 512) {
        const int hh = e % HDIM, dg = e / HDIM;
        const float4 v = *reinterpret_cast<const float4*>(
            W + (size_t)hh * (2 * D) + 4 * dg);              // A = W[:, 0:D]
        AT[(4 * dg + 0) * HDIM + hh] = v.x; AT[(4 * dg + 1) * HDIM + hh] = v.y;
        AT[(4 * dg + 2) * HDIM + hh] = v.z; AT[(4 * dg + 3) * HDIM + hh] = v.w;
    }
    __syncthreads();

    const int* __restrict__ tIdx = topIdx + (size_t)(rowBase + row) * KNN + wkb * KPT;
    const float* nrow[KPT];
    #pragma unroll
    for (int r = 0; r < KPT; ++r)
        nrow[r] = X + (size_t)tIdx[r] * D;

    float acc0[KPT], acc1[KPT];
    #pragma unroll
    for (int r = 0; r < KPT; ++r) { acc0[r] = 0.f; acc1[r] = 0.f; }

    for (int dg = 0; dg < D / 4; ++dg) {
        float4 b[KPT];
        #pragma unroll
        for (int r = 0; r < KPT; ++r)
            b[r] = *reinterpret_cast<const float4*>(nrow[r] + 4 * dg);
        const float2 a0 = *reinterpret_cast<const float2*>(&AT[(4 * dg + 0) * HDIM + hh2]);
        const float2 a1 = *reinterpret_cast<const float2*>(&AT[(4 * dg + 1) * HDIM + hh2]);
        const float2 a2 = *reinterpret_cast<const float2*>(&AT[(4 * dg + 2) * HDIM + hh2]);
        const float2 a3 = *reinterpret_cast<const float2*>(&AT[(4 * dg + 3) * HDIM + hh2]);
        #pragma unroll
        for (int r = 0; r < KPT; ++r) {
            acc0[r] = fmaf(a0.x, b[r].x, acc0[r]); acc1[r] = fmaf(a0.y, b[r].x, acc1[r]);
            acc0[r] = fmaf(a1.x, b[r].y, acc0[r]); acc1[r] = fmaf(a1.y, b[r].y, acc1[r]);
            acc0[r] = fmaf(a2.x, b[r].z, acc0[r]); acc1[r] = fmaf(a2.y, b[r].z, acc1[r]);
            acc0[r] = fmaf(a3.x, b[r].w, acc0[r]); acc1[r] = fmaf(a3.y, b[r].w, acc1[r]);
        }
    }

    float p0 = 0.f, p1 = 0.f;
    #pragma unroll
    for (int r = 0; r < KPT; ++r) {
        p0 += fminf(1.f, fmaxf(-1.f, acc0[r] + hs0));
        p1 += fminf(1.f, fmaxf(-1.f, acc1[r] + hs1));
    }
    *reinterpret_cast<float2*>(&part[row][wkb][hh2]) =
        make_float2(p0 * (1.f / KNN), p1 * (1.f / KNN));
    __syncthreads();

    {
        const int og   = t / SPL2;
        const int spl  = t % SPL2;
        const int orow = og >> 6, o = og & 63;
        const int c0   = spl * CL;
        float s = 0.f;
        for (int c = c0; c < c0 + CL; ++c) {
            float vsrc;
            if (c < HDIM) {
                vsrc = part[orow][0][c] + part[orow][1][c]
                     + part[orow][2][c] + part[orow][3][c];
            } else {
                vsrc = xi[orow][c - HDIM];
            }
            s = fmaf(vsrc, W2[(size_t)o * W2C + c], s);
        }
        #pragma unroll
        for (int off = SPL2 / 2; off; off >>= 1) s += __shfl_down(s, off);
        if (spl == 0) {
            if (LAYER == 0)
                out[(size_t)(rowBase + orow) * 128 + 64 + o] = s;
            else
                out[(size_t)(rowBase + orow) * ODIM + o] = s;
        }
    }
    if (LAYER == 0 && t < RPB * 64) {
        const int orow = t >> 6, d = t & 63;
        out[(size_t)(rowBase + orow) * 128 + d] = xi[orow][d];
    }
}

extern "C" void kernel_launch(void* const* d_in, const int* in_sizes, int n_in,
                              void* d_out, int out_size, void* d_ws, size_t ws_size,
                              hipStream_t stream) {
    const float* x    = (const float*)d_in[0];
    const float* w0   = (const float*)d_in[1];
    const float* w2_0 = (const float*)d_in[2];
    const float* w1   = (const float*)d_in[3];
    const float* w2_1 = (const float*)d_in[4];
    float* out = (float*)d_out;

    char* ws = (char*)d_ws;
    float* sq  = (float*)ws;                                          // 64 KB
    int*   idx = (int*)(ws + (size_t)NP * 4);                         // 2 MB
    float* x1  = (float*)(ws + (size_t)NP * 4 + (size_t)NP * KNN * 4);  // 8 MB
    unsigned short* xhi = (unsigned short*)(ws + (size_t)NP * 4
                          + (size_t)NP * KNN * 4 + (size_t)NP * HDIM * 4);  // 4 MB
    unsigned short* xlo = xhi + (size_t)NP * HDIM;                    // 4 MB

    // layer 0 (D = 64)
    split_kernel<<<NP * 64 / 4 / 256, 256, 0, stream>>>(x, xhi, xlo, NP * 64 / 4);
    sq_kernel<64><<<NP / 4, 256, 0, stream>>>(x, sq);
    topk_kernel<64><<<NP / 32, 512, 0, stream>>>(xhi, xlo, sq, idx);
    mlp_kernel<64, 0><<<NP / 2, 512, 0, stream>>>(x, idx, w0, w2_0, x1);

    // layer 1 (D = 128, x1 = [x, o0])
    split_kernel<<<NP * 128 / 4 / 256, 256, 0, stream>>>(x1, xhi, xlo, NP * 128 / 4);
    sq_kernel<128><<<NP / 4, 256, 0, stream>>>(x1, sq);
    topk_kernel<128><<<NP / 32, 512, 0, stream>>>(xhi, xlo, sq, idx);
    mlp_kernel<128, 1><<<NP / 2, 512, 0, stream>>>(x1, idx, w1, w2_1, out);
}

// Round 17
// 2404.889 us; speedup vs baseline: 1.1334x; 1.1334x over previous
//
#include <hip/hip_runtime.h>
#include <hip/hip_bf16.h>

#define NP   16384
#define KNN  32
#define HDIM 128
#define ODIM 64

typedef __attribute__((ext_vector_type(8))) short bf16x8;
typedef __attribute__((ext_vector_type(4))) float f32x4;

// ---------------- split fp32 -> bf16 (hi, lo) planes ----------------
__global__ __launch_bounds__(256)
void split_kernel(const float* __restrict__ X, unsigned short* __restrict__ hi,
                  unsigned short* __restrict__ lo, int n4) {
    const int i = blockIdx.x * 256 + threadIdx.x;
    if (i >= n4) return;
    const float4 v = reinterpret_cast<const float4*>(X)[i];
    const float vv[4] = {v.x, v.y, v.z, v.w};
    ushort4 h, l;
    unsigned short* hp = &h.x;
    unsigned short* lp = &l.x;
    #pragma unroll
    for (int c = 0; c < 4; ++c) {
        __hip_bfloat16 hb = __float2bfloat16(vv[c]);           // RNE
        const float hf = __bfloat162float(hb);
        __hip_bfloat16 lb = __float2bfloat16(vv[c] - hf);
        hp[c] = *reinterpret_cast<unsigned short*>(&hb);
        lp[c] = *reinterpret_cast<unsigned short*>(&lb);
    }
    reinterpret_cast<ushort4*>(hi)[i] = h;
    reinterpret_cast<ushort4*>(lo)[i] = l;
}

// ---------------- squared norms (fp32, exact as before) ----------------
template<int D>
__global__ __launch_bounds__(256)
void sq_kernel(const float* __restrict__ X, float* __restrict__ sq) {
    const int lane = threadIdx.x & 63;
    const int row  = blockIdx.x * 4 + (threadIdx.x >> 6);
    float s = 0.f;
    #pragma unroll
    for (int d = lane; d < D; d += 64) {
        const float v = X[(size_t)row * D + d];
        s = fmaf(v, v, s);
    }
    #pragma unroll
    for (int off = 32; off; off >>= 1) s += __shfl_down(s, off);
    if (lane == 0) sq[row] = s;
}

// ---------------- top-32 neighbors: MFMA scores + sorted register top-k ----
// score = hi.hi + hi.lo + lo.hi (bf16 split, fp32 accum) - 0.5*sq_j.
// TI=16 rows/block (A-frags 32 regs, not 64), JC=128, 8 waves; wave w owns
// cols [16w,16w+16).  xj staged to LDS via ASYNC global_load_lds (width 16,
// linear LDS dest + inverse-XOR-swizzled per-lane global src; XOR is an
// involution so the swizzled B-read is unchanged -> scores bit-identical to
// R14/R15).  No staging VGPRs -> total regs ~90 -> 4 waves/SIMD (enforced
// by __launch_bounds__(512,4)); LDS 73.8 KB -> 2 blocks/CU.
template<int D>
__global__ __launch_bounds__(512, 4)
void topk_kernel(const unsigned short* __restrict__ Xhi,
                 const unsigned short* __restrict__ Xlo,
                 const float* __restrict__ sq, int* __restrict__ topIdx) {
    constexpr int TI = 16, JC = 128, SS = JC + 1;
    constexpr int NT = NP / JC;
    constexpr int KQ = D / 8;            // 16B k-groups per row
    constexpr int KS = D / 32;           // MFMA k-steps
    constexpr int PLSLOT = JC * KQ;      // 16B slots per plane
    constexpr int CALLS = 2 * PLSLOT / 512;   // global_load_lds calls per wave
    __shared__ __align__(16) unsigned short xjB[2 * PLSLOT * 8];  // hi | lo
    __shared__ float scoresR[TI * SS];   // [row][col], stride 129

    const int t = threadIdx.x;
    const int lane = t & 63;
    const int waveU = __builtin_amdgcn_readfirstlane(t >> 6);
    const int rowBase = blockIdx.x * TI;
    const int l15 = lane & 15, l4 = lane >> 4;
    const float INF = __builtin_inff();
    const int jcol = 16 * waveU + l15;

    // A fragments (16 xi rows), resident in registers for the whole kernel.
    bf16x8 Ahi[KS], Alo[KS];
    #pragma unroll
    for (int s = 0; s < KS; ++s) {
        const size_t off = (size_t)(rowBase + l15) * D + 32 * s + 8 * l4;
        Ahi[s] = *reinterpret_cast<const bf16x8*>(Xhi + off);
        Alo[s] = *reinterpret_cast<const bf16x8*>(Xlo + off);
    }

    float tv[2]; int tidx[2]; float minv[2];
    #pragma unroll
    for (int r = 0; r < 2; ++r) { tv[r] = -INF; tidx[r] = 0x7fffffff; minv[r] = -INF; }

    // async staging: linear LDS slots, per-lane inverse-swizzled global src
    auto stageTile = [&](int jb) {
        #pragma unroll
        for (int c = 0; c < CALLS; ++c) {
            const int slotBase = (waveU * CALLS + c) * 64;   // wave-uniform
            const int sl = slotBase + lane;
            const int pl = sl / PLSLOT;                       // 0=hi, 1=lo
            const int ps = sl % PLSLOT;
            const int j  = ps / KQ;
            const int kq = (ps % KQ) ^ (j & (KQ - 1));        // involution
            const unsigned short* src =
                (pl ? Xlo : Xhi) + (size_t)(jb + j) * D + 8 * kq;
            __builtin_amdgcn_global_load_lds(
                (const __attribute__((address_space(1))) void*)src,
                (__attribute__((address_space(3))) void*)&xjB[(size_t)slotBase * 8],
                16, 0, 0);
        }
    };

    stageTile(0);
    __syncthreads();                     // drains vmcnt -> tile 0 in LDS

    for (int it = 0; it < NT; ++it) {
        const int jb = it * JC;
        const float sub0 = 0.5f * sq[jb + lane];
        const float sub1 = 0.5f * sq[jb + 64 + lane];

        // MFMA: this wave's 16 cols x 16 rows; 3 independent chains
        f32x4 Ca = {0,0,0,0}, Cb = {0,0,0,0}, Cc = {0,0,0,0};
        #pragma unroll
        for (int s = 0; s < KS; ++s) {
            const int kq = 4 * s + l4;
            const int slot = jcol * KQ + (kq ^ (jcol & (KQ - 1)));
            const bf16x8 Bh = *reinterpret_cast<const bf16x8*>(&xjB[(size_t)slot * 8]);
            const bf16x8 Bl = *reinterpret_cast<const bf16x8*>(&xjB[(size_t)(PLSLOT + slot) * 8]);
            Ca = __builtin_amdgcn_mfma_f32_16x16x32_bf16(Ahi[s], Bh, Ca, 0, 0, 0);
            Cb = __builtin_amdgcn_mfma_f32_16x16x32_bf16(Ahi[s], Bl, Cb, 0, 0, 0);
            Cc = __builtin_amdgcn_mfma_f32_16x16x32_bf16(Alo[s], Bh, Cc, 0, 0, 0);
        }
        // scatter C -> scoresR[row][col] (stride 129)
        #pragma unroll
        for (int r = 0; r < 4; ++r)
            scoresR[(4 * l4 + r) * SS + jcol] = (Ca[r] + Cb[r]) + Cc[r];
        __syncthreads();                 // B1: xjB reads + score writes done

        if (it + 1 < NT) stageTile(jb + JC);   // async; lands during scan

        // scan: sorted-insert; wave owns rows [2*waveU, 2*waveU+2)
        #pragma unroll
        for (int h = 0; h < 2; ++h) {
            float sv[2];
            unsigned long long m[2];
            #pragma unroll
            for (int r = 0; r < 2; ++r) {
                sv[r] = scoresR[(2 * waveU + r) * SS + h * 64 + lane]
                      - (h ? sub1 : sub0);
                m[r] = __ballot(sv[r] > minv[r]);
            }
            while (m[0] | m[1]) {
                #pragma unroll
                for (int r = 0; r < 2; ++r) {
                    if (m[r]) {
                        const int l = __builtin_ctzll(m[r]);  // ascending j => stable
                        m[r] &= m[r] - 1;
                        const float cv = __shfl(sv[r], l);
                        const int   cj = jb + h * 64 + l;
                        const float upv = __shfl_up(tv[r], 1);   // hoisted off chain
                        const int   upi = __shfl_up(tidx[r], 1);
                        const bool ge = (lane < KNN) && (tv[r] >= cv);
                        const int p = __popcll(__ballot(ge));    // ==32 -> no-op
                        if (lane == p)                   { tv[r] = cv;  tidx[r] = cj; }
                        else if (lane > p && lane < KNN) { tv[r] = upv; tidx[r] = upi; }
                    }
                }
            }
        }
        #pragma unroll
        for (int r = 0; r < 2; ++r)
            minv[r] = __shfl(tv[r], KNN - 1);   // exact refresh, once per tile

        __syncthreads();                 // B2: drains vmcnt -> next tile in LDS
    }

    if (lane < KNN) {
        #pragma unroll
        for (int r = 0; r < 2; ++r)
            topIdx[(size_t)(rowBase + waveU * 2 + r) * KNN + lane] = tidx[r];
    }
}

// ---------------- gather + MLP + pool + out (unchanged) ----------------
template<int D, int LAYER>
__global__ __launch_bounds__(512)
void mlp_kernel(const float* __restrict__ X, const int* __restrict__ topIdx,
                const float* __restrict__ W, const float* __restrict__ W2,
                float* __restrict__ out) {
    constexpr int RPB = 2, WPR = 4, KPT = 8;
    constexpr int W2C  = HDIM + D;
    constexpr int SPL2 = 512 / (RPB * ODIM);   // 4
    constexpr int CL   = W2C / SPL2;
    __shared__ float AT[D * HDIM];             // [d][hh]: B^T first, then A^T
    __shared__ float xi[RPB][D];
    __shared__ float part[RPB][WPR][HDIM];

    const int t = threadIdx.x;
    const int lane = t & 63;
    const int waveU = __builtin_amdgcn_readfirstlane(t >> 6);
    const int rowBase = blockIdx.x * RPB;
    const int row = waveU / WPR;
    const int wkb = waveU % WPR;
    const int hh2 = 2 * lane;

    if (t < RPB * D / 4) {
        const int i = t / (D / 4), dg = t % (D / 4);
        const float4 v = *reinterpret_cast<const float4*>(
            X + (size_t)(rowBase + i) * D + 4 * dg);
        xi[i][4 * dg + 0] = v.x; xi[i][4 * dg + 1] = v.y;
        xi[i][4 * dg + 2] = v.z; xi[i][4 * dg + 3] = v.w;
    }
    for (int e = t; e < HDIM * D / 4; e += 512) {
        const int hh = e % HDIM, dg = e / HDIM;
        const float4 v = *reinterpret_cast<const float4*>(
            W + (size_t)hh * (2 * D) + D + 4 * dg);          // B = W[:, D:2D]
        AT[(4 * dg + 0) * HDIM + hh] = v.x; AT[(4 * dg + 1) * HDIM + hh] = v.y;
        AT[(4 * dg + 2) * HDIM + hh] = v.z; AT[(4 * dg + 3) * HDIM + hh] = v.w;
    }
    __syncthreads();

    float hs0 = 0.f, hs1 = 0.f;
    #pragma unroll 8
    for (int d = 0; d < D; ++d) {
        const float a = xi[row][d];
        const float2 b = *reinterpret_cast<const float2*>(&AT[d * HDIM + hh2]);
        hs0 = fmaf(b.x, a, hs0);
        hs1 = fmaf(b.y, a, hs1);
    }
    __syncthreads();

    for (int e = t; e < HDIM * D / 4; e += 512) {
        const int hh = e % HDIM, dg = e / HDIM;
        const float4 v = *reinterpret_cast<const float4*>(
            W + (size_t)hh * (2 * D) + 4 * dg);              // A = W[:, 0:D]
        AT[(4 * dg + 0) * HDIM + hh] = v.x; AT[(4 * dg + 1) * HDIM + hh] = v.y;
        AT[(4 * dg + 2) * HDIM + hh] = v.z; AT[(4 * dg + 3) * HDIM + hh] = v.w;
    }
    __syncthreads();

    const int* __restrict__ tIdx = topIdx + (size_t)(rowBase + row) * KNN + wkb * KPT;
    const float* nrow[KPT];
    #pragma unroll
    for (int r = 0; r < KPT; ++r)
        nrow[r] = X + (size_t)tIdx[r] * D;

    float acc0[KPT], acc1[KPT];
    #pragma unroll
    for (int r = 0; r < KPT; ++r) { acc0[r] = 0.f; acc1[r] = 0.f; }

    for (int dg = 0; dg < D / 4; ++dg) {
        float4 b[KPT];
        #pragma unroll
        for (int r = 0; r < KPT; ++r)
            b[r] = *reinterpret_cast<const float4*>(nrow[r] + 4 * dg);
        const float2 a0 = *reinterpret_cast<const float2*>(&AT[(4 * dg + 0) * HDIM + hh2]);
        const float2 a1 = *reinterpret_cast<const float2*>(&AT[(4 * dg + 1) * HDIM + hh2]);
        const float2 a2 = *reinterpret_cast<const float2*>(&AT[(4 * dg + 2) * HDIM + hh2]);
        const float2 a3 = *reinterpret_cast<const float2*>(&AT[(4 * dg + 3) * HDIM + hh2]);
        #pragma unroll
        for (int r = 0; r < KPT; ++r) {
            acc0[r] = fmaf(a0.x, b[r].x, acc0[r]); acc1[r] = fmaf(a0.y, b[r].x, acc1[r]);
            acc0[r] = fmaf(a1.x, b[r].y, acc0[r]); acc1[r] = fmaf(a1.y, b[r].y, acc1[r]);
            acc0[r] = fmaf(a2.x, b[r].z, acc0[r]); acc1[r] = fmaf(a2.y, b[r].z, acc1[r]);
            acc0[r] = fmaf(a3.x, b[r].w, acc0[r]); acc1[r] = fmaf(a3.y, b[r].w, acc1[r]);
        }
    }

    float p0 = 0.f, p1 = 0.f;
    #pragma unroll
    for (int r = 0; r < KPT; ++r) {
        p0 += fminf(1.f, fmaxf(-1.f, acc0[r] + hs0));
        p1 += fminf(1.f, fmaxf(-1.f, acc1[r] + hs1));
    }
    *reinterpret_cast<float2*>(&part[row][wkb][hh2]) =
        make_float2(p0 * (1.f / KNN), p1 * (1.f / KNN));
    __syncthreads();

    {
        const int og   = t / SPL2;
        const int spl  = t % SPL2;
        const int orow = og >> 6, o = og & 63;
        const int c0   = spl * CL;
        float s = 0.f;
        for (int c = c0; c < c0 + CL; ++c) {
            float vsrc;
            if (c < HDIM) {
                vsrc = part[orow][0][c] + part[orow][1][c]
                     + part[orow][2][c] + part[orow][3][c];
            } else {
                vsrc = xi[orow][c - HDIM];
            }
            s = fmaf(vsrc, W2[(size_t)o * W2C + c], s);
        }
        #pragma unroll
        for (int off = SPL2 / 2; off; off >>= 1) s += __shfl_down(s, off);
        if (spl == 0) {
            if (LAYER == 0)
                out[(size_t)(rowBase + orow) * 128 + 64 + o] = s;
            else
                out[(size_t)(rowBase + orow) * ODIM + o] = s;
        }
    }
    if (LAYER == 0 && t < RPB * 64) {
        const int orow = t >> 6, d = t & 63;
        out[(size_t)(rowBase + orow) * 128 + d] = xi[orow][d];
    }
}

extern "C" void kernel_launch(void* const* d_in, const int* in_sizes, int n_in,
                              void* d_out, int out_size, void* d_ws, size_t ws_size,
                              hipStream_t stream) {
    const float* x    = (const float*)d_in[0];
    const float* w0   = (const float*)d_in[1];
    const float* w2_0 = (const float*)d_in[2];
    const float* w1   = (const float*)d_in[3];
    const float* w2_1 = (const float*)d_in[4];
    float* out = (float*)d_out;

    char* ws = (char*)d_ws;
    float* sq  = (float*)ws;                                          // 64 KB
    int*   idx = (int*)(ws + (size_t)NP * 4);                         // 2 MB
    float* x1  = (float*)(ws + (size_t)NP * 4 + (size_t)NP * KNN * 4);  // 8 MB
    unsigned short* xhi = (unsigned short*)(ws + (size_t)NP * 4
                          + (size_t)NP * KNN * 4 + (size_t)NP * HDIM * 4);  // 4 MB
    unsigned short* xlo = xhi + (size_t)NP * HDIM;                    // 4 MB

    // layer 0 (D = 64)
    split_kernel<<<NP * 64 / 4 / 256, 256, 0, stream>>>(x, xhi, xlo, NP * 64 / 4);
    sq_kernel<64><<<NP / 4, 256, 0, stream>>>(x, sq);
    topk_kernel<64><<<NP / 16, 512, 0, stream>>>(xhi, xlo, sq, idx);
    mlp_kernel<64, 0><<<NP / 2, 512, 0, stream>>>(x, idx, w0, w2_0, x1);

    // layer 1 (D = 128, x1 = [x, o0])
    split_kernel<<<NP * 128 / 4 / 256, 256, 0, stream>>>(x1, xhi, xlo, NP * 128 / 4);
    sq_kernel<128><<<NP / 4, 256, 0, stream>>>(x1, sq);
    topk_kernel<128><<<NP / 16, 512, 0, stream>>>(xhi, xlo, sq, idx);
    mlp_kernel<128, 1><<<NP / 2, 512, 0, stream>>>(x1, idx, w1, w2_1, out);
}

// Round 18
// 2125.695 us; speedup vs baseline: 1.2822x; 1.1313x over previous
//
#include <hip/hip_runtime.h>
#include <hip/hip_bf16.h>

#define NP   16384
#define KNN  32
#define HDIM 128
#define ODIM 64

typedef __attribute__((ext_vector_type(8))) short bf16x8;
typedef __attribute__((ext_vector_type(4))) float f32x4;

// ---------------- split fp32 -> bf16 (hi, lo) planes ----------------
__global__ __launch_bounds__(256)
void split_kernel(const float* __restrict__ X, unsigned short* __restrict__ hi,
                  unsigned short* __restrict__ lo, int n4) {
    const int i = blockIdx.x * 256 + threadIdx.x;
    if (i >= n4) return;
    const float4 v = reinterpret_cast<const float4*>(X)[i];
    const float vv[4] = {v.x, v.y, v.z, v.w};
    ushort4 h, l;
    unsigned short* hp = &h.x;
    unsigned short* lp = &l.x;
    #pragma unroll
    for (int c = 0; c < 4; ++c) {
        __hip_bfloat16 hb = __float2bfloat16(vv[c]);           // RNE
        const float hf = __bfloat162float(hb);
        __hip_bfloat16 lb = __float2bfloat16(vv[c] - hf);
        hp[c] = *reinterpret_cast<unsigned short*>(&hb);
        lp[c] = *reinterpret_cast<unsigned short*>(&lb);
    }
    reinterpret_cast<ushort4*>(hi)[i] = h;
    reinterpret_cast<ushort4*>(lo)[i] = l;
}

// ---------------- squared norms (fp32, exact as before) ----------------
template<int D>
__global__ __launch_bounds__(256)
void sq_kernel(const float* __restrict__ X, float* __restrict__ sq) {
    const int lane = threadIdx.x & 63;
    const int row  = blockIdx.x * 4 + (threadIdx.x >> 6);
    float s = 0.f;
    #pragma unroll
    for (int d = lane; d < D; d += 64) {
        const float v = X[(size_t)row * D + d];
        s = fmaf(v, v, s);
    }
    #pragma unroll
    for (int off = 32; off; off >>= 1) s += __shfl_down(s, off);
    if (lane == 0) sq[row] = s;
}

// ---------------- top-32 neighbors: MFMA scores + sorted register top-k ----
// (unchanged from round 17 -- passed, best measured)
template<int D>
__global__ __launch_bounds__(512, 4)
void topk_kernel(const unsigned short* __restrict__ Xhi,
                 const unsigned short* __restrict__ Xlo,
                 const float* __restrict__ sq, int* __restrict__ topIdx) {
    constexpr int TI = 16, JC = 128, SS = JC + 1;
    constexpr int NT = NP / JC;
    constexpr int KQ = D / 8;            // 16B k-groups per row
    constexpr int KS = D / 32;           // MFMA k-steps
    constexpr int PLSLOT = JC * KQ;      // 16B slots per plane
    constexpr int CALLS = 2 * PLSLOT / 512;   // global_load_lds calls per wave
    __shared__ __align__(16) unsigned short xjB[2 * PLSLOT * 8];  // hi | lo
    __shared__ float scoresR[TI * SS];   // [row][col], stride 129

    const int t = threadIdx.x;
    const int lane = t & 63;
    const int waveU = __builtin_amdgcn_readfirstlane(t >> 6);
    const int rowBase = blockIdx.x * TI;
    const int l15 = lane & 15, l4 = lane >> 4;
    const float INF = __builtin_inff();
    const int jcol = 16 * waveU + l15;

    // A fragments (16 xi rows), resident in registers for the whole kernel.
    bf16x8 Ahi[KS], Alo[KS];
    #pragma unroll
    for (int s = 0; s < KS; ++s) {
        const size_t off = (size_t)(rowBase + l15) * D + 32 * s + 8 * l4;
        Ahi[s] = *reinterpret_cast<const bf16x8*>(Xhi + off);
        Alo[s] = *reinterpret_cast<const bf16x8*>(Xlo + off);
    }

    float tv[2]; int tidx[2]; float minv[2];
    #pragma unroll
    for (int r = 0; r < 2; ++r) { tv[r] = -INF; tidx[r] = 0x7fffffff; minv[r] = -INF; }

    // async staging: linear LDS slots, per-lane inverse-swizzled global src
    auto stageTile = [&](int jb) {
        #pragma unroll
        for (int c = 0; c < CALLS; ++c) {
            const int slotBase = (waveU * CALLS + c) * 64;   // wave-uniform
            const int sl = slotBase + lane;
            const int pl = sl / PLSLOT;                       // 0=hi, 1=lo
            const int ps = sl % PLSLOT;
            const int j  = ps / KQ;
            const int kq = (ps % KQ) ^ (j & (KQ - 1));        // involution
            const unsigned short* src =
                (pl ? Xlo : Xhi) + (size_t)(jb + j) * D + 8 * kq;
            __builtin_amdgcn_global_load_lds(
                (const __attribute__((address_space(1))) void*)src,
                (__attribute__((address_space(3))) void*)&xjB[(size_t)slotBase * 8],
                16, 0, 0);
        }
    };

    stageTile(0);
    __syncthreads();                     // drains vmcnt -> tile 0 in LDS

    for (int it = 0; it < NT; ++it) {
        const int jb = it * JC;
        const float sub0 = 0.5f * sq[jb + lane];
        const float sub1 = 0.5f * sq[jb + 64 + lane];

        // MFMA: this wave's 16 cols x 16 rows; 3 independent chains
        f32x4 Ca = {0,0,0,0}, Cb = {0,0,0,0}, Cc = {0,0,0,0};
        #pragma unroll
        for (int s = 0; s < KS; ++s) {
            const int kq = 4 * s + l4;
            const int slot = jcol * KQ + (kq ^ (jcol & (KQ - 1)));
            const bf16x8 Bh = *reinterpret_cast<const bf16x8*>(&xjB[(size_t)slot * 8]);
            const bf16x8 Bl = *reinterpret_cast<const bf16x8*>(&xjB[(size_t)(PLSLOT + slot) * 8]);
            Ca = __builtin_amdgcn_mfma_f32_16x16x32_bf16(Ahi[s], Bh, Ca, 0, 0, 0);
            Cb = __builtin_amdgcn_mfma_f32_16x16x32_bf16(Ahi[s], Bl, Cb, 0, 0, 0);
            Cc = __builtin_amdgcn_mfma_f32_16x16x32_bf16(Alo[s], Bh, Cc, 0, 0, 0);
        }
        // scatter C -> scoresR[row][col] (stride 129)
        #pragma unroll
        for (int r = 0; r < 4; ++r)
            scoresR[(4 * l4 + r) * SS + jcol] = (Ca[r] + Cb[r]) + Cc[r];
        __syncthreads();                 // B1: xjB reads + score writes done

        if (it + 1 < NT) stageTile(jb + JC);   // async; lands during scan

        // scan: sorted-insert; wave owns rows [2*waveU, 2*waveU+2)
        #pragma unroll
        for (int h = 0; h < 2; ++h) {
            float sv[2];
            unsigned long long m[2];
            #pragma unroll
            for (int r = 0; r < 2; ++r) {
                sv[r] = scoresR[(2 * waveU + r) * SS + h * 64 + lane]
                      - (h ? sub1 : sub0);
                m[r] = __ballot(sv[r] > minv[r]);
            }
            while (m[0] | m[1]) {
                #pragma unroll
                for (int r = 0; r < 2; ++r) {
                    if (m[r]) {
                        const int l = __builtin_ctzll(m[r]);  // ascending j => stable
                        m[r] &= m[r] - 1;
                        const float cv = __shfl(sv[r], l);
                        const int   cj = jb + h * 64 + l;
                        const float upv = __shfl_up(tv[r], 1);   // hoisted off chain
                        const int   upi = __shfl_up(tidx[r], 1);
                        const bool ge = (lane < KNN) && (tv[r] >= cv);
                        const int p = __popcll(__ballot(ge));    // ==32 -> no-op
                        if (lane == p)                   { tv[r] = cv;  tidx[r] = cj; }
                        else if (lane > p && lane < KNN) { tv[r] = upv; tidx[r] = upi; }
                    }
                }
            }
        }
        #pragma unroll
        for (int r = 0; r < 2; ++r)
            minv[r] = __shfl(tv[r], KNN - 1);   // exact refresh, once per tile

        __syncthreads();                 // B2: drains vmcnt -> next tile in LDS
    }

    if (lane < KNN) {
        #pragma unroll
        for (int r = 0; r < 2; ++r)
            topIdx[(size_t)(rowBase + waveU * 2 + r) * KNN + lane] = tidx[r];
    }
}

// ---------------- gather + MLP + pool + out ----------------
// h_k = A@nbr_k + B@x; pooled = mean_k clip(h_k); out = [pooled, x] @ W2^T.
// THIS ROUND: neighbors gathered into LDS [row][k][d] (d-fastest, coalesced
// float4 writes, conflict-free) -> GEMM is PURE-DS (wave-uniform b128
// broadcast nbr reads + b64 A^T reads; in-order lgkmcnt, compiler-pipelined;
// no s_load/ds_read lgkmcnt-mixing drains).  Epilogue float4-vectorized
// (accumulation order preserved).  Values bit-identical to R17.
template<int D, int LAYER>
__global__ __launch_bounds__(512)
void mlp_kernel(const float* __restrict__ X, const int* __restrict__ topIdx,
                const float* __restrict__ W, const float* __restrict__ W2,
                float* __restrict__ out) {
    constexpr int RPB = 2, WPR = 4, KPT = 8;   // 8 waves = RPB rows x WPR k-groups
    constexpr int W2C  = HDIM + D;
    constexpr int SPL2 = 512 / (RPB * ODIM);   // 4
    constexpr int CL   = W2C / SPL2;           // 48 (D=64) / 64 (D=128)
    __shared__ float AT[D * HDIM];             // [d][hh]: B^T first, then A^T
    __shared__ float nbrL[RPB][KNN][D];        // gathered neighbors, d-fastest
    __shared__ float xi[RPB][D];
    __shared__ float part[RPB][WPR][HDIM];
    __shared__ int   idx_s[RPB][KNN];

    const int t = threadIdx.x;
    const int lane = t & 63;
    const int waveU = __builtin_amdgcn_readfirstlane(t >> 6);
    const int rowBase = blockIdx.x * RPB;
    const int row = waveU / WPR;
    const int wkb = waveU % WPR;
    const int hh2 = 2 * lane;

    // phase 0: xi, neighbor indices, stage B^T
    if (t < RPB * D / 4) {
        const int i = t / (D / 4), dg = t % (D / 4);
        const float4 v = *reinterpret_cast<const float4*>(
            X + (size_t)(rowBase + i) * D + 4 * dg);
        xi[i][4 * dg + 0] = v.x; xi[i][4 * dg + 1] = v.y;
        xi[i][4 * dg + 2] = v.z; xi[i][4 * dg + 3] = v.w;
    }
    if (t < RPB * KNN)
        idx_s[t >> 5][t & 31] = topIdx[(size_t)(rowBase + (t >> 5)) * KNN + (t & 31)];
    for (int e = t; e < HDIM * D / 4; e += 512) {
        const int hh = e % HDIM, dg = e / HDIM;
        const float4 v = *reinterpret_cast<const float4*>(
            W + (size_t)hh * (2 * D) + D + 4 * dg);          // B = W[:, D:2D]
        AT[(4 * dg + 0) * HDIM + hh] = v.x; AT[(4 * dg + 1) * HDIM + hh] = v.y;
        AT[(4 * dg + 2) * HDIM + hh] = v.z; AT[(4 * dg + 3) * HDIM + hh] = v.w;
    }
    __syncthreads();

    // phase 1: hself (lane's 2 hh) in registers
    float hs0 = 0.f, hs1 = 0.f;
    #pragma unroll 8
    for (int d = 0; d < D; ++d) {
        const float a = xi[row][d];
        const float2 b = *reinterpret_cast<const float2*>(&AT[d * HDIM + hh2]);
        hs0 = fmaf(b.x, a, hs0);
        hs1 = fmaf(b.y, a, hs1);
    }
    __syncthreads();

    // phase 2: restage A^T; gather neighbors -> LDS (d-fastest, coalesced)
    for (int e = t; e < HDIM * D / 4; e += 512) {
        const int hh = e % HDIM, dg = e / HDIM;
        const float4 v = *reinterpret_cast<const float4*>(
            W + (size_t)hh * (2 * D) + 4 * dg);              // A = W[:, 0:D]
        AT[(4 * dg + 0) * HDIM + hh] = v.x; AT[(4 * dg + 1) * HDIM + hh] = v.y;
        AT[(4 * dg + 2) * HDIM + hh] = v.z; AT[(4 * dg + 3) * HDIM + hh] = v.w;
    }
    constexpr int G4 = RPB * KNN * D / 4;
    for (int e = t; e < G4; e += 512) {
        const int d4 = e % (D / 4);
        const int k  = (e / (D / 4)) % KNN;
        const int r  = e / (D / 4 * KNN);
        const float4 v = *reinterpret_cast<const float4*>(
            X + (size_t)idx_s[r][k] * D + 4 * d4);
        *reinterpret_cast<float4*>(&nbrL[r][k][4 * d4]) = v;
    }
    __syncthreads();

    // phase 3: GEMM (pure-DS) + clip + pool
    float acc0[KPT], acc1[KPT];
    #pragma unroll
    for (int r = 0; r < KPT; ++r) { acc0[r] = 0.f; acc1[r] = 0.f; }

    for (int dg = 0; dg < D / 4; ++dg) {
        float4 b[KPT];
        #pragma unroll
        for (int r = 0; r < KPT; ++r)          // wave-uniform -> b128 broadcast
            b[r] = *reinterpret_cast<const float4*>(&nbrL[row][wkb * KPT + r][4 * dg]);
        const float2 a0 = *reinterpret_cast<const float2*>(&AT[(4 * dg + 0) * HDIM + hh2]);
        const float2 a1 = *reinterpret_cast<const float2*>(&AT[(4 * dg + 1) * HDIM + hh2]);
        const float2 a2 = *reinterpret_cast<const float2*>(&AT[(4 * dg + 2) * HDIM + hh2]);
        const float2 a3 = *reinterpret_cast<const float2*>(&AT[(4 * dg + 3) * HDIM + hh2]);
        #pragma unroll
        for (int r = 0; r < KPT; ++r) {        // d-ascending accumulation
            acc0[r] = fmaf(a0.x, b[r].x, acc0[r]); acc1[r] = fmaf(a0.y, b[r].x, acc1[r]);
            acc0[r] = fmaf(a1.x, b[r].y, acc0[r]); acc1[r] = fmaf(a1.y, b[r].y, acc1[r]);
            acc0[r] = fmaf(a2.x, b[r].z, acc0[r]); acc1[r] = fmaf(a2.y, b[r].z, acc1[r]);
            acc0[r] = fmaf(a3.x, b[r].w, acc0[r]); acc1[r] = fmaf(a3.y, b[r].w, acc1[r]);
        }
    }

    float p0 = 0.f, p1 = 0.f;
    #pragma unroll
    for (int r = 0; r < KPT; ++r) {
        p0 += fminf(1.f, fmaxf(-1.f, acc0[r] + hs0));
        p1 += fminf(1.f, fmaxf(-1.f, acc1[r] + hs1));
    }
    *reinterpret_cast<float2*>(&part[row][wkb][hh2]) =
        make_float2(p0 * (1.f / KNN), p1 * (1.f / KNN));
    __syncthreads();

    // phase 4: out = [pooled, x] @ W2^T (float4 loads, scalar-order accum)
    {
        const int og   = t / SPL2;
        const int spl  = t % SPL2;
        const int orow = og >> 6, o = og & 63;
        const int c0   = spl * CL;
        float s = 0.f;
        for (int c4 = 0; c4 < CL / 4; ++c4) {
            const int c = c0 + 4 * c4;
            const float4 w = *reinterpret_cast<const float4*>(W2 + (size_t)o * W2C + c);
            float vs[4];
            if (c < HDIM) {                    // chunks are side-pure (4-aligned)
                const float4 q0 = *reinterpret_cast<const float4*>(&part[orow][0][c]);
                const float4 q1 = *reinterpret_cast<const float4*>(&part[orow][1][c]);
                const float4 q2 = *reinterpret_cast<const float4*>(&part[orow][2][c]);
                const float4 q3 = *reinterpret_cast<const float4*>(&part[orow][3][c]);
                vs[0] = q0.x + q1.x + q2.x + q3.x;
                vs[1] = q0.y + q1.y + q2.y + q3.y;
                vs[2] = q0.z + q1.z + q2.z + q3.z;
                vs[3] = q0.w + q1.w + q2.w + q3.w;
            } else {
                const float4 xv = *reinterpret_cast<const float4*>(&xi[orow][c - HDIM]);
                vs[0] = xv.x; vs[1] = xv.y; vs[2] = xv.z; vs[3] = xv.w;
            }
            const float wv[4] = {w.x, w.y, w.z, w.w};
            #pragma unroll
            for (int j = 0; j < 4; ++j)        // sequential: same order as scalar
                s = fmaf(vs[j], wv[j], s);
        }
        #pragma unroll
        for (int off = SPL2 / 2; off; off >>= 1) s += __shfl_down(s, off);
        if (spl == 0) {
            if (LAYER == 0)
                out[(size_t)(rowBase + orow) * 128 + 64 + o] = s;  // x1 cols 64..127
            else
                out[(size_t)(rowBase + orow) * ODIM + o] = s;      // final output
        }
    }
    if (LAYER == 0 && t < RPB * 64) {
        const int orow = t >> 6, d = t & 63;
        out[(size_t)(rowBase + orow) * 128 + d] = xi[orow][d];     // x1 cols 0..63
    }
}

extern "C" void kernel_launch(void* const* d_in, const int* in_sizes, int n_in,
                              void* d_out, int out_size, void* d_ws, size_t ws_size,
                              hipStream_t stream) {
    const float* x    = (const float*)d_in[0];
    const float* w0   = (const float*)d_in[1];
    const float* w2_0 = (const float*)d_in[2];
    const float* w1   = (const float*)d_in[3];
    const float* w2_1 = (const float*)d_in[4];
    float* out = (float*)d_out;

    char* ws = (char*)d_ws;
    float* sq  = (float*)ws;                                          // 64 KB
    int*   idx = (int*)(ws + (size_t)NP * 4);                         // 2 MB
    float* x1  = (float*)(ws + (size_t)NP * 4 + (size_t)NP * KNN * 4);  // 8 MB
    unsigned short* xhi = (unsigned short*)(ws + (size_t)NP * 4
                          + (size_t)NP * KNN * 4 + (size_t)NP * HDIM * 4);  // 4 MB
    unsigned short* xlo = xhi + (size_t)NP * HDIM;                    // 4 MB

    // layer 0 (D = 64)
    split_kernel<<<NP * 64 / 4 / 256, 256, 0, stream>>>(x, xhi, xlo, NP * 64 / 4);
    sq_kernel<64><<<NP / 4, 256, 0, stream>>>(x, sq);
    topk_kernel<64><<<NP / 16, 512, 0, stream>>>(xhi, xlo, sq, idx);
    mlp_kernel<64, 0><<<NP / 2, 512, 0, stream>>>(x, idx, w0, w2_0, x1);

    // layer 1 (D = 128, x1 = [x, o0])
    split_kernel<<<NP * 128 / 4 / 256, 256, 0, stream>>>(x1, xhi, xlo, NP * 128 / 4);
    sq_kernel<128><<<NP / 4, 256, 0, stream>>>(x1, sq);
    topk_kernel<128><<<NP / 16, 512, 0, stream>>>(xhi, xlo, sq, idx);
    mlp_kernel<128, 1><<<NP / 2, 512, 0, stream>>>(x1, idx, w1, w2_1, out);
}

// Round 19
// 1971.606 us; speedup vs baseline: 1.3824x; 1.0782x over previous
//
#include <hip/hip_runtime.h>
#include <hip/hip_bf16.h>

#define NP   16384
#define KNN  32
#define HDIM 128
#define ODIM 64

typedef __attribute__((ext_vector_type(8))) short bf16x8;
typedef __attribute__((ext_vector_type(4))) float f32x4;

// ---------------- split fp32 -> bf16 (hi, lo) planes ----------------
__global__ __launch_bounds__(256)
void split_kernel(const float* __restrict__ X, unsigned short* __restrict__ hi,
                  unsigned short* __restrict__ lo, int n4) {
    const int i = blockIdx.x * 256 + threadIdx.x;
    if (i >= n4) return;
    const float4 v = reinterpret_cast<const float4*>(X)[i];
    const float vv[4] = {v.x, v.y, v.z, v.w};
    ushort4 h, l;
    unsigned short* hp = &h.x;
    unsigned short* lp = &l.x;
    #pragma unroll
    for (int c = 0; c < 4; ++c) {
        __hip_bfloat16 hb = __float2bfloat16(vv[c]);           // RNE
        const float hf = __bfloat162float(hb);
        __hip_bfloat16 lb = __float2bfloat16(vv[c] - hf);
        hp[c] = *reinterpret_cast<unsigned short*>(&hb);
        lp[c] = *reinterpret_cast<unsigned short*>(&lb);
    }
    reinterpret_cast<ushort4*>(hi)[i] = h;
    reinterpret_cast<ushort4*>(lo)[i] = l;
}

// split A-half of W ([HDIM][2D] -> cols 0..D-1) into bf16 hi/lo [HDIM][D]
__global__ __launch_bounds__(256)
void wsplit_kernel(const float* __restrict__ W, unsigned short* __restrict__ hi,
                   unsigned short* __restrict__ lo, int Dd) {
    const int i = blockIdx.x * 256 + threadIdx.x;
    if (i >= HDIM * Dd) return;
    const int hh = i / Dd, d = i % Dd;
    const float v = W[(size_t)hh * (2 * Dd) + d];
    __hip_bfloat16 hb = __float2bfloat16(v);
    const float hf = __bfloat162float(hb);
    __hip_bfloat16 lb = __float2bfloat16(v - hf);
    hi[i] = *reinterpret_cast<unsigned short*>(&hb);
    lo[i] = *reinterpret_cast<unsigned short*>(&lb);
}

// ---------------- squared norms (fp32, exact as before) ----------------
template<int D>
__global__ __launch_bounds__(256)
void sq_kernel(const float* __restrict__ X, float* __restrict__ sq) {
    const int lane = threadIdx.x & 63;
    const int row  = blockIdx.x * 4 + (threadIdx.x >> 6);
    float s = 0.f;
    #pragma unroll
    for (int d = lane; d < D; d += 64) {
        const float v = X[(size_t)row * D + d];
        s = fmaf(v, v, s);
    }
    #pragma unroll
    for (int off = 32; off; off >>= 1) s += __shfl_down(s, off);
    if (lane == 0) sq[row] = s;
}

// ---------------- top-32 neighbors: MFMA scores + sorted register top-k ----
// (unchanged from round 17/18 -- passed, best measured)
template<int D>
__global__ __launch_bounds__(512, 4)
void topk_kernel(const unsigned short* __restrict__ Xhi,
                 const unsigned short* __restrict__ Xlo,
                 const float* __restrict__ sq, int* __restrict__ topIdx) {
    constexpr int TI = 16, JC = 128, SS = JC + 1;
    constexpr int NT = NP / JC;
    constexpr int KQ = D / 8;            // 16B k-groups per row
    constexpr int KS = D / 32;           // MFMA k-steps
    constexpr int PLSLOT = JC * KQ;      // 16B slots per plane
    constexpr int CALLS = 2 * PLSLOT / 512;   // global_load_lds calls per wave
    __shared__ __align__(16) unsigned short xjB[2 * PLSLOT * 8];  // hi | lo
    __shared__ float scoresR[TI * SS];   // [row][col], stride 129

    const int t = threadIdx.x;
    const int lane = t & 63;
    const int waveU = __builtin_amdgcn_readfirstlane(t >> 6);
    const int rowBase = blockIdx.x * TI;
    const int l15 = lane & 15, l4 = lane >> 4;
    const float INF = __builtin_inff();
    const int jcol = 16 * waveU + l15;

    // A fragments (16 xi rows), resident in registers for the whole kernel.
    bf16x8 Ahi[KS], Alo[KS];
    #pragma unroll
    for (int s = 0; s < KS; ++s) {
        const size_t off = (size_t)(rowBase + l15) * D + 32 * s + 8 * l4;
        Ahi[s] = *reinterpret_cast<const bf16x8*>(Xhi + off);
        Alo[s] = *reinterpret_cast<const bf16x8*>(Xlo + off);
    }

    float tv[2]; int tidx[2]; float minv[2];
    #pragma unroll
    for (int r = 0; r < 2; ++r) { tv[r] = -INF; tidx[r] = 0x7fffffff; minv[r] = -INF; }

    // async staging: linear LDS slots, per-lane inverse-swizzled global src
    auto stageTile = [&](int jb) {
        #pragma unroll
        for (int c = 0; c < CALLS; ++c) {
            const int slotBase = (waveU * CALLS + c) * 64;   // wave-uniform
            const int sl = slotBase + lane;
            const int pl = sl / PLSLOT;                       // 0=hi, 1=lo
            const int ps = sl % PLSLOT;
            const int j  = ps / KQ;
            const int kq = (ps % KQ) ^ (j & (KQ - 1));        // involution
            const unsigned short* src =
                (pl ? Xlo : Xhi) + (size_t)(jb + j) * D + 8 * kq;
            __builtin_amdgcn_global_load_lds(
                (const __attribute__((address_space(1))) void*)src,
                (__attribute__((address_space(3))) void*)&xjB[(size_t)slotBase * 8],
                16, 0, 0);
        }
    };

    stageTile(0);
    __syncthreads();                     // drains vmcnt -> tile 0 in LDS

    for (int it = 0; it < NT; ++it) {
        const int jb = it * JC;
        const float sub0 = 0.5f * sq[jb + lane];
        const float sub1 = 0.5f * sq[jb + 64 + lane];

        // MFMA: this wave's 16 cols x 16 rows; 3 independent chains
        f32x4 Ca = {0,0,0,0}, Cb = {0,0,0,0}, Cc = {0,0,0,0};
        #pragma unroll
        for (int s = 0; s < KS; ++s) {
            const int kq = 4 * s + l4;
            const int slot = jcol * KQ + (kq ^ (jcol & (KQ - 1)));
            const bf16x8 Bh = *reinterpret_cast<const bf16x8*>(&xjB[(size_t)slot * 8]);
            const bf16x8 Bl = *reinterpret_cast<const bf16x8*>(&xjB[(size_t)(PLSLOT + slot) * 8]);
            Ca = __builtin_amdgcn_mfma_f32_16x16x32_bf16(Ahi[s], Bh, Ca, 0, 0, 0);
            Cb = __builtin_amdgcn_mfma_f32_16x16x32_bf16(Ahi[s], Bl, Cb, 0, 0, 0);
            Cc = __builtin_amdgcn_mfma_f32_16x16x32_bf16(Alo[s], Bh, Cc, 0, 0, 0);
        }
        // scatter C -> scoresR[row][col] (stride 129)
        #pragma unroll
        for (int r = 0; r < 4; ++r)
            scoresR[(4 * l4 + r) * SS + jcol] = (Ca[r] + Cb[r]) + Cc[r];
        __syncthreads();                 // B1: xjB reads + score writes done

        if (it + 1 < NT) stageTile(jb + JC);   // async; lands during scan

        // scan: sorted-insert; wave owns rows [2*waveU, 2*waveU+2)
        #pragma unroll
        for (int h = 0; h < 2; ++h) {
            float sv[2];
            unsigned long long m[2];
            #pragma unroll
            for (int r = 0; r < 2; ++r) {
                sv[r] = scoresR[(2 * waveU + r) * SS + h * 64 + lane]
                      - (h ? sub1 : sub0);
                m[r] = __ballot(sv[r] > minv[r]);
            }
            while (m[0] | m[1]) {
                #pragma unroll
                for (int r = 0; r < 2; ++r) {
                    if (m[r]) {
                        const int l = __builtin_ctzll(m[r]);  // ascending j => stable
                        m[r] &= m[r] - 1;
                        const float cv = __shfl(sv[r], l);
                        const int   cj = jb + h * 64 + l;
                        const float upv = __shfl_up(tv[r], 1);   // hoisted off chain
                        const int   upi = __shfl_up(tidx[r], 1);
                        const bool ge = (lane < KNN) && (tv[r] >= cv);
                        const int p = __popcll(__ballot(ge));    // ==32 -> no-op
                        if (lane == p)                   { tv[r] = cv;  tidx[r] = cj; }
                        else if (lane > p && lane < KNN) { tv[r] = upv; tidx[r] = upi; }
                    }
                }
            }
        }
        #pragma unroll
        for (int r = 0; r < 2; ++r)
            minv[r] = __shfl(tv[r], KNN - 1);   // exact refresh, once per tile

        __syncthreads();                 // B2: drains vmcnt -> next tile in LDS
    }

    if (lane < KNN) {
        #pragma unroll
        for (int r = 0; r < 2; ++r)
            topIdx[(size_t)(rowBase + waveU * 2 + r) * KNN + lane] = tidx[r];
    }
}

// ---------------- gather + MLP (MFMA) + pool + out ----------------
// h_k = A@nbr_k + B@x (A via bf16-split MFMA; B@x f32 VALU); pooled =
// mean_k clip(h_k); out = [pooled, x] @ W2^T.
// Wave w owns hh-tile [16w,16w+16): A-frags resident in VGPRs.  Loop over
// (row, kTile): B-frags = neighbor rows from Xhi/Xlo directly (per-lane
// fragment layout).  Pool via 4-step shfl_xor over the 16 k-lanes.
template<int D, int LAYER>
__global__ __launch_bounds__(512, 4)
void mlp_kernel(const float* __restrict__ X,
                const unsigned short* __restrict__ Xhi,
                const unsigned short* __restrict__ Xlo,
                const unsigned short* __restrict__ WAhi,
                const unsigned short* __restrict__ WAlo,
                const float* __restrict__ W, const float* __restrict__ W2,
                const int* __restrict__ topIdx, float* __restrict__ out) {
    constexpr int RPB = 2;
    constexpr int KS = D / 32;
    constexpr int W2C  = HDIM + D;
    constexpr int SPL2 = 4;
    constexpr int CL   = W2C / SPL2;
    __shared__ float AT[D * HDIM];          // B^T, for hself only
    __shared__ float xi[RPB][D];
    __shared__ float hself_s[RPB][HDIM];
    __shared__ float part[RPB][2][HDIM];    // per-kTile pooled partials
    __shared__ int   idx_s[RPB][KNN];

    const int t = threadIdx.x;
    const int lane = t & 63;
    const int waveU = __builtin_amdgcn_readfirstlane(t >> 6);
    const int rowBase = blockIdx.x * RPB;
    const int l15 = lane & 15, l4 = lane >> 4;

    // phase 0: xi, idx, stage B^T; A-frags issued early (global, independent)
    if (t < RPB * D / 4) {
        const int i = t / (D / 4), dg = t % (D / 4);
        const float4 v = *reinterpret_cast<const float4*>(
            X + (size_t)(rowBase + i) * D + 4 * dg);
        xi[i][4 * dg + 0] = v.x; xi[i][4 * dg + 1] = v.y;
        xi[i][4 * dg + 2] = v.z; xi[i][4 * dg + 3] = v.w;
    }
    if (t < RPB * KNN)
        idx_s[t >> 5][t & 31] = topIdx[(size_t)(rowBase + (t >> 5)) * KNN + (t & 31)];
    bf16x8 Ahi[KS], Alo[KS];
    #pragma unroll
    for (int s = 0; s < KS; ++s) {
        const size_t off = (size_t)(waveU * 16 + l15) * D + 32 * s + 8 * l4;
        Ahi[s] = *reinterpret_cast<const bf16x8*>(WAhi + off);
        Alo[s] = *reinterpret_cast<const bf16x8*>(WAlo + off);
    }
    for (int e = t; e < HDIM * D / 4; e += 512) {
        const int hh = e % HDIM, dg = e / HDIM;
        const float4 v = *reinterpret_cast<const float4*>(
            W + (size_t)hh * (2 * D) + D + 4 * dg);          // B = W[:, D:2D]
        AT[(4 * dg + 0) * HDIM + hh] = v.x; AT[(4 * dg + 1) * HDIM + hh] = v.y;
        AT[(4 * dg + 2) * HDIM + hh] = v.z; AT[(4 * dg + 3) * HDIM + hh] = v.w;
    }
    __syncthreads();

    // phase 1: hself = B @ x (f32, 256 threads; AT reads are 2-way broadcast)
    if (t < RPB * HDIM) {
        const int row = t >> 7, hh = t & 127;
        float s = 0.f;
        #pragma unroll 8
        for (int d = 0; d < D; ++d)
            s = fmaf(AT[d * HDIM + hh], xi[row][d], s);
        hself_s[row][hh] = s;
    }
    __syncthreads();

    // phase 2: MFMA GEMM; wave's hh-tile x (row, kTile)
    #pragma unroll
    for (int a = 0; a < 4; ++a) {
        const int row = a >> 1, kT = a & 1;
        const int nIdx = idx_s[row][kT * 16 + l15];
        bf16x8 Bh[KS], Bl[KS];
        #pragma unroll
        for (int s = 0; s < KS; ++s) {
            const size_t off = (size_t)nIdx * D + 32 * s + 8 * l4;
            Bh[s] = *reinterpret_cast<const bf16x8*>(Xhi + off);
            Bl[s] = *reinterpret_cast<const bf16x8*>(Xlo + off);
        }
        f32x4 Ca = {0,0,0,0}, Cb = {0,0,0,0}, Cc = {0,0,0,0};
        #pragma unroll
        for (int s = 0; s < KS; ++s) {
            Ca = __builtin_amdgcn_mfma_f32_16x16x32_bf16(Ahi[s], Bh[s], Ca, 0, 0, 0);
            Cb = __builtin_amdgcn_mfma_f32_16x16x32_bf16(Ahi[s], Bl[s], Cb, 0, 0, 0);
            Cc = __builtin_amdgcn_mfma_f32_16x16x32_bf16(Alo[s], Bh[s], Cc, 0, 0, 0);
        }
        // C: col(k)=l15, row(hh)=16*waveU + 4*l4 + r.  clip + pool over k.
        float ps[4];
        #pragma unroll
        for (int r = 0; r < 4; ++r) {
            const float h = (Ca[r] + Cb[r]) + Cc[r]
                          + hself_s[row][waveU * 16 + 4 * l4 + r];
            ps[r] = fminf(1.f, fmaxf(-1.f, h));
        }
        #pragma unroll
        for (int off = 1; off <= 8; off <<= 1)
            #pragma unroll
            for (int r = 0; r < 4; ++r)
                ps[r] += __shfl_xor(ps[r], off);
        if (l15 == 0)
            #pragma unroll
            for (int r = 0; r < 4; ++r)
                part[row][kT][waveU * 16 + 4 * l4 + r] = ps[r] * (1.f / KNN);
    }
    __syncthreads();

    // phase 3: out = [pooled, x] @ W2^T (float4 loads, scalar-order accum)
    {
        const int og   = t / SPL2;
        const int spl  = t % SPL2;
        const int orow = og >> 6, o = og & 63;
        const int c0   = spl * CL;
        float s = 0.f;
        for (int c4 = 0; c4 < CL / 4; ++c4) {
            const int c = c0 + 4 * c4;
            const float4 w = *reinterpret_cast<const float4*>(W2 + (size_t)o * W2C + c);
            float vs[4];
            if (c < HDIM) {                    // float4 chunks are side-pure
                const float4 q0 = *reinterpret_cast<const float4*>(&part[orow][0][c]);
                const float4 q1 = *reinterpret_cast<const float4*>(&part[orow][1][c]);
                vs[0] = q0.x + q1.x; vs[1] = q0.y + q1.y;
                vs[2] = q0.z + q1.z; vs[3] = q0.w + q1.w;
            } else {
                const float4 xv = *reinterpret_cast<const float4*>(&xi[orow][c - HDIM]);
                vs[0] = xv.x; vs[1] = xv.y; vs[2] = xv.z; vs[3] = xv.w;
            }
            const float wv[4] = {w.x, w.y, w.z, w.w};
            #pragma unroll
            for (int j = 0; j < 4; ++j)
                s = fmaf(vs[j], wv[j], s);
        }
        #pragma unroll
        for (int off = SPL2 / 2; off; off >>= 1) s += __shfl_down(s, off);
        if (spl == 0) {
            if (LAYER == 0)
                out[(size_t)(rowBase + orow) * 128 + 64 + o] = s;  // x1 cols 64..127
            else
                out[(size_t)(rowBase + orow) * ODIM + o] = s;      // final output
        }
    }
    if (LAYER == 0 && t < RPB * 64) {
        const int orow = t >> 6, d = t & 63;
        out[(size_t)(rowBase + orow) * 128 + d] = xi[orow][d];     // x1 cols 0..63
    }
}

extern "C" void kernel_launch(void* const* d_in, const int* in_sizes, int n_in,
                              void* d_out, int out_size, void* d_ws, size_t ws_size,
                              hipStream_t stream) {
    const float* x    = (const float*)d_in[0];
    const float* w0   = (const float*)d_in[1];
    const float* w2_0 = (const float*)d_in[2];
    const float* w1   = (const float*)d_in[3];
    const float* w2_1 = (const float*)d_in[4];
    float* out = (float*)d_out;

    char* ws = (char*)d_ws;
    float* sq  = (float*)ws;                                          // 64 KB
    int*   idx = (int*)(ws + (size_t)NP * 4);                         // 2 MB
    float* x1  = (float*)(ws + (size_t)NP * 4 + (size_t)NP * KNN * 4);  // 8 MB
    unsigned short* xhi = (unsigned short*)(ws + (size_t)NP * 4
                          + (size_t)NP * KNN * 4 + (size_t)NP * HDIM * 4);  // 4 MB
    unsigned short* xlo = xhi + (size_t)NP * HDIM;                    // 4 MB
    unsigned short* wa0hi = xlo + (size_t)NP * HDIM;                  // 16 KB
    unsigned short* wa0lo = wa0hi + HDIM * 64;
    unsigned short* wa1hi = wa0lo + HDIM * 64;                        // 32 KB
    unsigned short* wa1lo = wa1hi + HDIM * 128;

    // weight splits (independent of data flow)
    wsplit_kernel<<<(HDIM * 64 + 255) / 256, 256, 0, stream>>>(w0, wa0hi, wa0lo, 64);
    wsplit_kernel<<<(HDIM * 128 + 255) / 256, 256, 0, stream>>>(w1, wa1hi, wa1lo, 128);

    // layer 0 (D = 64)
    split_kernel<<<NP * 64 / 4 / 256, 256, 0, stream>>>(x, xhi, xlo, NP * 64 / 4);
    sq_kernel<64><<<NP / 4, 256, 0, stream>>>(x, sq);
    topk_kernel<64><<<NP / 16, 512, 0, stream>>>(xhi, xlo, sq, idx);
    mlp_kernel<64, 0><<<NP / 2, 512, 0, stream>>>(x, xhi, xlo, wa0hi, wa0lo,
                                                  w0, w2_0, idx, x1);

    // layer 1 (D = 128, x1 = [x, o0])
    split_kernel<<<NP * 128 / 4 / 256, 256, 0, stream>>>(x1, xhi, xlo, NP * 128 / 4);
    sq_kernel<128><<<NP / 4, 256, 0, stream>>>(x1, sq);
    topk_kernel<128><<<NP / 16, 512, 0, stream>>>(xhi, xlo, sq, idx);
    mlp_kernel<128, 1><<<NP / 2, 512, 0, stream>>>(x1, xhi, xlo, wa1hi, wa1lo,
                                                   w1, w2_1, idx, out);
}